// Round 3
// baseline (167.695 us; speedup 1.0000x reference)
//
#include <hip/hip_runtime.h>

// SurfNetwork: grid-hash gather + tiny MLP + transmittance cumprod + rgb reduce.
//
// Round-3 = round-2 structure with the nontemporal builtins fixed to use
// clang native vector types (ext_vector_type), which the builtin accepts.
//
// Structure: ONE WAVE (64 lanes) per batch row; lane t owns samples 2t and
// 2t+1. Per lane: 1 coalesced int4 index load + 4 independent float4 gathers
// in flight. Cumprod scan wave-local (shfl_up), rgb reduction wave-local
// (shfl_down) -> NO LDS, NO barriers. Weights/d read via wave-uniform
// addresses (readfirstlane'd row) -> scalar loads. dW0 = d[b]@W0[0:16,:] is
// sample-invariant, computed once per lane.
//
// x / sigma streamed once -> nontemporal, keeping L2/L3 for the 256 MB grid
// table (gathers fetch 64 B sectors for 16 B used -> FETCH ~535 MB structural).

typedef int   iv4 __attribute__((ext_vector_type(4)));
typedef float fv2 __attribute__((ext_vector_type(2)));

constexpr int ROWS_PER_BLOCK = 4;   // 4 waves = 256 threads per block

__global__ __launch_bounds__(256) void surf_kernel(
    const int*   __restrict__ x,      // [B, 128, 2]
    const float* __restrict__ dvec,   // [B, 16]
    const float* __restrict__ grid,   // [TABLE, 4]
    const float* __restrict__ W0,     // [22, 8] row-major
    const float* __restrict__ W1,     // [8, 3]  row-major
    float*       __restrict__ sigma_out, // [B, 128]
    float*       __restrict__ rgb_out,   // [B, 3]
    int B)
{
    const int lane = threadIdx.x & 63;
    const int wv   = threadIdx.x >> 6;
    const int row  = __builtin_amdgcn_readfirstlane(blockIdx.x * ROWS_PER_BLOCK + wv);
    if (row >= B) return;

    // ---- issue all memory ops up front --------------------------------
    // lane t covers samples 2t, 2t+1: ints [4t .. 4t+3] of this row of x.
    const iv4 idx = __builtin_nontemporal_load(
        (const iv4*)x + (size_t)row * 64 + lane);
    const float4 fa0 = ((const float4*)grid)[idx.x];
    const float4 fb0 = ((const float4*)grid)[idx.y];
    const float4 fa1 = ((const float4*)grid)[idx.z];
    const float4 fb1 = ((const float4*)grid)[idx.w];

    // ---- sample-invariant first-layer partial: dW0 = d[row] @ W0[0:16,:] ---
    const float* dp = dvec + (size_t)row * 16;
    float dW0[8];
    #pragma unroll
    for (int j = 0; j < 8; ++j) dW0[j] = 0.f;
    #pragma unroll
    for (int i = 0; i < 16; ++i) {
        const float di = dp[i];                 // wave-uniform -> s_load
        #pragma unroll
        for (int j = 0; j < 8; ++j)
            dW0[j] = fmaf(di, W0[i * 8 + j], dW0[j]);
    }

    // ---- per-sample sigma + MLP ---------------------------------------
    float s[2], col[2][3];
    #pragma unroll
    for (int q = 0; q < 2; ++q) {
        const float4 fa = q ? fa1 : fa0;
        const float4 fb = q ? fb1 : fb0;
        s[q] = 1.f / (1.f + __expf(-(fa.x * fb.x)));
        const float geo[6] = { fa.y, fa.z, fa.w, fb.y, fb.z, fb.w };
        float h[8];
        #pragma unroll
        for (int j = 0; j < 8; ++j) {
            float acc = dW0[j];
            #pragma unroll
            for (int i = 0; i < 6; ++i)
                acc = fmaf(geo[i], W0[(16 + i) * 8 + j], acc);  // W0: s_load
            h[j] = fmaxf(acc, 0.f);
        }
        #pragma unroll
        for (int c = 0; c < 3; ++c) {
            float acc = 0.f;
            #pragma unroll
            for (int k = 0; k < 8; ++k)
                acc = fmaf(h[k], W1[k * 3 + c], acc);
            col[q][c] = 1.f / (1.f + __expf(-acc));
        }
    }

    // ---- wave-local transmittance scan --------------------------------
    // p = product of (1-s) over this lane's pair; inclusive scan over lanes;
    // exclusive (shift-by-one) gives T at sample 2t.
    const float q0 = 1.f - s[0];
    float p = q0 * (1.f - s[1]);
    #pragma unroll
    for (int off = 1; off < 64; off <<= 1) {
        const float o = __shfl_up(p, off, 64);
        if (lane >= off) p *= o;
    }
    float T0 = __shfl_up(p, 1, 64);
    if (lane == 0) T0 = 1.f;
    const float T1 = T0 * q0;
    const float w0 = T0 * s[0];
    const float w1 = T1 * s[1];

    // ---- outputs -------------------------------------------------------
    const fv2 sv = { s[0], s[1] };
    __builtin_nontemporal_store(sv, (fv2*)sigma_out + (size_t)row * 64 + lane);

    float r0 = fmaf(w0, col[0][0], w1 * col[1][0]);
    float r1 = fmaf(w0, col[0][1], w1 * col[1][1]);
    float r2 = fmaf(w0, col[0][2], w1 * col[1][2]);
    #pragma unroll
    for (int off = 32; off > 0; off >>= 1) {
        r0 += __shfl_down(r0, off, 64);
        r1 += __shfl_down(r1, off, 64);
        r2 += __shfl_down(r2, off, 64);
    }
    if (lane == 0) {
        rgb_out[row * 3 + 0] = r0;
        rgb_out[row * 3 + 1] = r1;
        rgb_out[row * 3 + 2] = r2;
    }
}

extern "C" void kernel_launch(void* const* d_in, const int* in_sizes, int n_in,
                              void* d_out, int out_size, void* d_ws, size_t ws_size,
                              hipStream_t stream) {
    const int*   x    = (const int*)d_in[0];
    const float* dvec = (const float*)d_in[1];
    const float* grid = (const float*)d_in[2];
    const float* W0   = (const float*)d_in[3];
    const float* W1   = (const float*)d_in[4];

    const int B = in_sizes[1] / 16;          // d is [B, 16]

    float* sigma_out = (float*)d_out;                 // [B, 128]
    float* rgb_out   = sigma_out + (size_t)B * 128;   // [B, 3]

    const int grid_blocks = (B + ROWS_PER_BLOCK - 1) / ROWS_PER_BLOCK;
    surf_kernel<<<grid_blocks, ROWS_PER_BLOCK * 64, 0, stream>>>(
        x, dvec, grid, W0, W1, sigma_out, rgb_out, B);
}